// Round 5
// baseline (84.757 us; speedup 1.0000x reference)
//
#include <hip/hip_runtime.h>

#define LAM 0.5f
#define MU 0.1f
#define RHO 0.05f
#define CLS 10
#define ROWS 256
#define SG 16
#define L2E  1.4426950408889634f
#define HL2E 0.7213475204444817f
#define EINV 0.36787944117144233f

typedef const __attribute__((address_space(1))) char gchar;
typedef __attribute__((address_space(3))) char lchar;

__device__ __forceinline__ float waveReduceSum(float v) {
#pragma unroll
    for (int m = 1; m < 64; m <<= 1) v += __shfl_xor(v, m, 64);
    return v;
}

// Stage 2560 B (64 rows x 10 floats) per wave: global -> LDS direct DMA.
// Each wave's slice is PRIVATE: written by its own DMA, read only by its own
// lanes (thread tid reads row tid; rows 64w..64w+63 live in wave w's slice).
// => no __syncthreads needed; per-wave counted vmcnt is the only sync.
__device__ __forceinline__ void dmaTile(const float4* srcBase, float* dstBase,
                                        int wid, int lane) {
    const float4* s = srcBase + wid * 160;
    float* d = dstBase + wid * 640;
    __builtin_amdgcn_global_load_lds((gchar*)(const char*)(s + lane),
                                     (lchar*)(char*)d, 16, 0, 0);
    __builtin_amdgcn_global_load_lds((gchar*)(const char*)(s + 64 + lane),
                                     (lchar*)(char*)(d + 256), 16, 0, 0);
    if (lane < 32)
        __builtin_amdgcn_global_load_lds((gchar*)(const char*)(s + 128 + lane),
                                         (lchar*)(char*)(d + 512), 16, 0, 0);
}

// Fused kernel: per-chunk logp (recomputed per s-group, trivial) + streaming
// noise pass with double-buffered DMA staging, zero barriers in the loop.
__global__ __launch_bounds__(256) void main_kernel(
    const float* __restrict__ noise, const float* __restrict__ pred,
    const int* __restrict__ tgt,
    float* __restrict__ wstarPart, float* __restrict__ partials, int B) {
    __shared__ float buf0[ROWS * CLS];   // 10240 B
    __shared__ float buf1[ROWS * CLS];   // 10240 B
    __shared__ float part[4][SG][3];
    __shared__ float red[4];
    const int tid = threadIdx.x;
    const int lane = tid & 63, wid = tid >> 6;
    const int nChunks = B / ROWS;            // 256
    const int chunk = blockIdx.x % nChunks;
    const int sg = blockIdx.x / nChunks;
    const int rowBase = chunk * ROWS;
    const int s0 = sg * SG;

    // the ONLY non-DMA global load before the loop: issue first
    const int t = tgt[rowBase + tid];

    const float4* predT = (const float4*)(pred + (size_t)rowBase * CLS);
    const size_t sStride4 = (size_t)B * CLS / 4;
    const float4* noiseT = (const float4*)(noise + (size_t)rowBase * CLS)
                           + (size_t)s0 * sStride4;

    dmaTile(predT, buf0, wid, lane);    // pred -> buf0   (3 outstanding)
    dmaTile(noiseT, buf1, wid, lane);   // s0   -> buf1   (6 outstanding)
    asm volatile("s_waitcnt vmcnt(3)" ::: "memory");   // pred (oldest 3) done
    __builtin_amdgcn_sched_barrier(0);

    // ---- logp for this chunk (from wave-private buf0 slice) ----
    float x[CLS];
    {
        const float2* r2 = (const float2*)(buf0 + tid * CLS);
#pragma unroll
        for (int j = 0; j < 5; j++) { float2 v = r2[j]; x[2*j] = v.x; x[2*j+1] = v.y; }
    }
    float mx = x[0];
#pragma unroll
    for (int c = 1; c < CLS; c++) mx = fmaxf(mx, x[c]);
    float z = 0.f;
#pragma unroll
    for (int c = 0; c < CLS; c++) z += __expf(x[c] - mx);
    float lse = mx + __logf(z);

    float lp[CLS], lpk[CLS], kk[CLS], bias[CLS];
    float xt = 0.f;
#pragma unroll
    for (int c = 0; c < CLS; c++) {
        bool e = (c == t);
        float lpv = x[c] - lse;
        lp[c] = lpv;
        kk[c] = e ? EINV : 1.f;
        lpk[c] = lpv * kk[c];
        bias[c] = e ? L2E : 0.f;
        xt += e ? x[c] : 0.f;
    }
    {
        float rce = waveReduceSum(lse - xt);
        if (lane == 0) red[wid] = rce;
    }

    const float4* srcNext = noiseT + sStride4;

    // softmax(n+oh) via pl = exp2(fma(n,HL2E,bias)) = exp(n/2+oh):
    //   LAM-term uses pl directly; full term e = pl^2 * k (k = e^{-oh}).
#define BODY(CUR, NXT, SI)                                                     \
    {                                                                          \
        const int si = (SI);                                                   \
        if (si < SG - 1) {                                                     \
            dmaTile(srcNext, (NXT), wid, lane);                                \
            srcNext += sStride4;                                               \
            asm volatile("s_waitcnt vmcnt(3)" ::: "memory");                   \
        } else {                                                               \
            asm volatile("s_waitcnt vmcnt(0)" ::: "memory");                   \
        }                                                                      \
        __builtin_amdgcn_sched_barrier(0);                                     \
        float nn[CLS];                                                         \
        {                                                                      \
            const float2* r2 = (const float2*)((CUR) + tid * CLS);             \
            _Pragma("unroll")                                                  \
            for (int j = 0; j < 5; j++) {                                      \
                float2 v = r2[j]; nn[2*j] = v.x; nn[2*j+1] = v.y;              \
            }                                                                  \
        }                                                                      \
        float Z = 0.f, Zl = 0.f, dot = 0.f, dotl = 0.f, sq = 0.f;              \
        _Pragma("unroll")                                                      \
        for (int c = 0; c < CLS; c++) {                                        \
            float a  = fmaf(nn[c], HL2E, bias[c]);                             \
            float pl = exp2f(a);                                               \
            float t1 = pl * pl;                                                \
            Zl += pl;                                                          \
            dotl = fmaf(pl, lp[c], dotl);                                      \
            Z    = fmaf(t1, kk[c], Z);                                         \
            dot  = fmaf(t1, lpk[c], dot);                                      \
            sq   = fmaf(nn[c], nn[c], sq);                                     \
        }                                                                      \
        float rw  = waveReduceSum(__fdividef(dot, Z));                         \
        float rwt = waveReduceSum(__fdividef(dotl, Zl));                       \
        float rn2 = waveReduceSum(sq);                                         \
        if (lane == 0) {                                                       \
            part[wid][si][0] = rw;                                             \
            part[wid][si][1] = rwt;                                            \
            part[wid][si][2] = rn2;                                            \
        }                                                                      \
    }

    for (int sb = 0; sb < SG; sb += 2) {
        BODY(buf1, buf0, sb);
        BODY(buf0, buf1, sb + 1);
    }
#undef BODY

    __syncthreads();
    if (tid < SG * 3) {
        int si = tid / 3, ki = tid % 3;
        float v = part[0][si][ki] + part[1][si][ki] + part[2][si][ki] + part[3][si][ki];
        partials[((size_t)(s0 + si) * 3 + ki) * nChunks + chunk] = v;
    }
    if (sg == 0 && tid == 0)
        wstarPart[chunk] = red[0] + red[1] + red[2] + red[3];
}

// Single-block tail: reduce partials rows + wstarPart, hinge terms, scalar out.
// One launch replaces reduce_kernel + finalize_kernel.
__global__ __launch_bounds__(1024) void tail_kernel(
    const float* __restrict__ partials, const float* __restrict__ wstarPart,
    float* __restrict__ out, int B, int S, int nChunks) {
    __shared__ float sres[3 * 128];   // 3*S
    __shared__ float wred[4];
    __shared__ float scred[2];
    const int tid = threadIdx.x;
    const int lane = tid & 63, wid = tid >> 6;
    const int nRows = 3 * S;          // 384

    // Phase A: each wave reduces rows wid, wid+16, ... (256 floats each, coalesced)
    for (int r = wid; r < nRows; r += 16) {
        const float* row = partials + (size_t)r * nChunks;
        float v = 0.f;
#pragma unroll 4
        for (int j = lane; j < nChunks; j += 64) v += row[j];
        v = waveReduceSum(v);
        if (lane == 0) sres[r] = v;
    }

    // Phase B: waves 0..3 reduce wstarPart (nChunks floats)
    if (tid < 256) {
        float v = (tid < nChunks) ? wstarPart[tid] : 0.f;
        v = waveReduceSum(v);
        if (lane == 0) wred[wid] = v;
    }
    __syncthreads();

    // Phase C: hinge terms per s (threads 0..S-1), reduce, write scalar
    float invB = 1.0f / (float)B;
    float wstar = (wred[0] + wred[1] + wred[2] + wred[3]) * invB;
    float local = 0.f;
    if (tid < S) {
        float w  = -sres[3 * tid + 0] * invB;
        float wt = -sres[3 * tid + 1] * invB;
        float n2 =  sres[3 * tid + 2];
        float sc1 = fmaxf(wstar - wt, 0.f);
        float sc2 = fmaxf(wstar - w + MU * n2 * 0.5f, 0.f);
        float sc3 = fmaxf(wt - (1.f - LAM) * wstar + LAM * w
                          + MU * LAM * (1.f - LAM) * n2 * 0.5f, 0.f);
        local = sc1 + sc2 + sc3;
    }
    if (tid < 128) {
        float rsc = waveReduceSum(local);
        if (lane == 0) scred[wid] = rsc;
    }
    __syncthreads();
    if (tid == 0) out[0] = wstar + RHO * (scred[0] + scred[1]);
}

extern "C" void kernel_launch(void* const* d_in, const int* in_sizes, int n_in,
                              void* d_out, int out_size, void* d_ws, size_t ws_size,
                              hipStream_t stream) {
    const float* pred  = (const float*)d_in[0];
    const int*   tgt   = (const int*)d_in[1];
    const float* noise = (const float*)d_in[2];
    float* out = (float*)d_out;

    int B = in_sizes[1];                 // 65536
    int S = in_sizes[2] / in_sizes[0];   // 128
    int nChunks = B / ROWS;              // 256
    int nSG = S / SG;                    // 8

    float* ws = (float*)d_ws;
    float* wstarPart = ws;                // [nChunks]
    float* partials  = ws + nChunks;      // [S*3*nChunks]

    // every slot written deterministically each call -> no memset needed
    main_kernel<<<nSG * nChunks, 256, 0, stream>>>(noise, pred, tgt,
                                                   wstarPart, partials, B);
    tail_kernel<<<1, 1024, 0, stream>>>(partials, wstarPart, out, B, S, nChunks);
}